// Round 7
// baseline (191.329 us; speedup 1.0000x reference)
//
#include <hip/hip_runtime.h>
#include <math.h>

#define H_ 128
#define W_ 128
#define C_ 64
#define B_ 8
#define HW 16384          // H_*W_
#define NPIX (B_*HW)      // 131072

typedef __attribute__((ext_vector_type(8))) short short8;
typedef __attribute__((ext_vector_type(4))) float f32x4;

__device__ __forceinline__ float softplus_fast(float v) {
    return fmaxf(v, 0.f) + __logf(1.f + __expf(-fabsf(v)));
}

__device__ __forceinline__ unsigned short f2bf(float f) {
    unsigned u = __builtin_bit_cast(unsigned, f);
    unsigned r = (u + 0x7fffu + ((u >> 16) & 1u)) >> 16;
    return (unsigned short)r;
}

// K0: (a) transpose w2 [o][c][3][3] f32 -> bf16 MFMA A-fragments (wtr);
//     (b) blocks 0-1 also transpose w_reduce [o][c] -> bf16 A-frags (wtr1).
__global__ __launch_bounds__(256) void k0_wtr(const float* __restrict__ w2,
                                              const float* __restrict__ wr,
                                              unsigned short* __restrict__ wtr,
                                              unsigned short* __restrict__ wtr1)
{
    int t = blockIdx.x * 256 + threadIdx.x;
    if (t < 512) {
        int lane = t & 63, f = t >> 6;
        int mt = f >> 1, kh = f & 1;
        int o  = mt * 16 + (lane & 15);
        int c0 = kh * 32 + ((lane >> 4) << 3);
        uint4 pk;
        unsigned short* pv = (unsigned short*)&pk;
#pragma unroll
        for (int e = 0; e < 8; ++e)
            pv[e] = f2bf(wr[o * C_ + c0 + e]);
        *(uint4*)&wtr1[(size_t)t * 8] = pk;
    }
    if (t >= 4 * 18 * 64) return;
    int lane = t & 63;
    int f    = (t >> 6) % 18;
    int wv   = t / (18 * 64);
    int koff = f >> 1, ch = f & 1;
    int o = wv * 16 + (lane & 15);
    int cb = ch * 32 + ((lane >> 4) << 3);
    uint4 pk;
    unsigned short* pv = (unsigned short*)&pk;
#pragma unroll
    for (int e = 0; e < 8; ++e)
        pv[e] = f2bf(w2[(size_t)o * 576 + (size_t)(cb + e) * 9 + koff]);
    *(uint4*)&wtr[(size_t)t * 8] = pk;
}

// K1: r = W_reduce @ x + b_reduce via MFMA implicit GEMM.
__global__ __launch_bounds__(256) void k1_mfma(
    const float* __restrict__ x, const unsigned short* __restrict__ wtr1,
    const float* __restrict__ br, unsigned short* __restrict__ rb)
{
    __shared__ unsigned short xb[256 * 64];   // 32KB, chunk-XOR swizzled
    __shared__ float brs[C_];
    int tid = threadIdx.x;
    int blk = blockIdx.x;
    int pid0 = blk << 8;
    int b    = pid0 >> 14;
    int rem0 = pid0 & (HW - 1);
    const float* xbase = x + (((size_t)b * C_) << 14) + rem0;

    if (tid < C_) brs[tid] = br[tid];

    int p = tid;
#pragma unroll
    for (int m = 0; m < 8; ++m) {
        float tmp[8];
#pragma unroll
        for (int e = 0; e < 8; ++e)
            tmp[e] = xbase[((size_t)(m * 8 + e) << 14) + p];
        unsigned pk[4];
#pragma unroll
        for (int e = 0; e < 4; ++e)
            pk[e] = (unsigned)f2bf(tmp[2 * e]) | ((unsigned)f2bf(tmp[2 * e + 1]) << 16);
        *(uint4*)&xb[(p << 6) + ((m ^ (p & 7)) << 3)] = *(uint4*)pk;
    }

    int wid = tid >> 6, lane = tid & 63;
    int nl  = lane & 15;
    int kg  = lane >> 4;

    short8 af[8];
    const short8* wp = (const short8*)wtr1;
#pragma unroll
    for (int f = 0; f < 8; ++f) af[f] = wp[f * 64 + lane];

    f32x4 acc[4][4];
#pragma unroll
    for (int mt = 0; mt < 4; ++mt)
#pragma unroll
        for (int nt = 0; nt < 4; ++nt) acc[mt][nt] = (f32x4){0.f, 0.f, 0.f, 0.f};

    __syncthreads();

    int nbase = wid << 6;
#pragma unroll
    for (int nt = 0; nt < 4; ++nt) {
        int pp = nbase + (nt << 4) + nl;
#pragma unroll
        for (int kh = 0; kh < 2; ++kh) {
            int m = kh * 4 + kg;
            short8 bf = *(const short8*)&xb[(pp << 6) + ((m ^ (pp & 7)) << 3)];
#pragma unroll
            for (int mt = 0; mt < 4; ++mt)
                acc[mt][nt] = __builtin_amdgcn_mfma_f32_16x16x32_bf16(
                    af[mt * 2 + kh], bf, acc[mt][nt], 0, 0, 0);
        }
    }

    __syncthreads();

#pragma unroll
    for (int mt = 0; mt < 4; ++mt) {
        int c = (mt << 4) + (kg << 2);
        float b0 = brs[c], b1 = brs[c + 1], b2v = brs[c + 2], b3 = brs[c + 3];
        int chunk = c >> 3;
#pragma unroll
        for (int nt = 0; nt < 4; ++nt) {
            int pp = nbase + (nt << 4) + nl;
            f32x4 a = acc[mt][nt];
            unsigned lo = (unsigned)f2bf(a[0] + b0) | ((unsigned)f2bf(a[1] + b1) << 16);
            unsigned hi = (unsigned)f2bf(a[2] + b2v) | ((unsigned)f2bf(a[3] + b3) << 16);
            unsigned* dst = (unsigned*)&xb[(pp << 6) + ((chunk ^ (pp & 7)) << 3) + ((kg & 1) << 2)];
            dst[0] = lo;
            dst[1] = hi;
        }
    }
    __syncthreads();

    uint4* rp = (uint4*)(rb + ((size_t)(pid0 + p) << 6));
#pragma unroll
    for (int m = 0; m < 8; ++m)
        rp[m] = *(const uint4*)&xb[(p << 6) + ((m ^ (p & 7)) << 3)];
}

// K1b: per-channel sum/sumsq over rb (bf16 pixel-major).
__global__ __launch_bounds__(256) void k1b_stats(
    const unsigned short* __restrict__ rb, float* __restrict__ stats)
{
    __shared__ float ls[128];
    int tid = threadIdx.x;
    if (tid < 128) ls[tid] = 0.f;
    __syncthreads();

    int j   = tid & 7;
    int row = (blockIdx.x << 5) + (tid >> 3);
    float s[8] = {0,0,0,0,0,0,0,0}, q[8] = {0,0,0,0,0,0,0,0};
    for (int p = row; p < NPIX; p += (gridDim.x << 5)) {
        uint4 v = *(const uint4*)(rb + ((size_t)p << 6) + (j << 3));
        const unsigned* u = (const unsigned*)&v;
#pragma unroll
        for (int e = 0; e < 4; ++e) {
            float lo = __builtin_bit_cast(float, u[e] << 16);
            float hi = __builtin_bit_cast(float, u[e] & 0xffff0000u);
            s[2*e]   += lo; q[2*e]   += lo * lo;
            s[2*e+1] += hi; q[2*e+1] += hi * hi;
        }
    }
#pragma unroll
    for (int e = 0; e < 8; ++e) {
#pragma unroll
        for (int m = 8; m <= 32; m <<= 1) {
            s[e] += __shfl_xor(s[e], m, 64);
            q[e] += __shfl_xor(q[e], m, 64);
        }
    }
    int lane = tid & 63;
    if (lane < 8) {
#pragma unroll
        for (int e = 0; e < 8; ++e) {
            atomicAdd(&ls[lane * 8 + e], s[e]);
            atomicAdd(&ls[64 + lane * 8 + e], q[e]);
        }
    }
    __syncthreads();
    if (tid < 128) atomicAdd(&stats[tid], ls[tid]);
}

// K3 v2: double-buffered bf16-pair halo staging (loads issued a full compute
// phase early — T14), 8 barriers total, linear-tid LDS staging addresses
// precomputed once. kern[9] streamed from r; z via per-thread LDS row.
__global__ __launch_bounds__(256) void k3_involution(
    const float* __restrict__ x, const unsigned short* __restrict__ rb,
    const float* __restrict__ stats, const float* __restrict__ gamma,
    const float* __restrict__ beta, const float* __restrict__ wspan,
    const float* __restrict__ bspan, unsigned short* __restrict__ zb)
{
    __shared__ float wst[C_ * 12];
    __shared__ float a_s[C_], c_s[C_];
    __shared__ unsigned xh[2][4 * 324];   // packed bf16 ch-pairs, dbuf (10.4KB)
    __shared__ unsigned zs[256 * 32];     // 32KB z staging
    int tid = threadIdx.x;
    for (int i = tid; i < 9 * C_; i += 256) {
        int k = i >> 6, o = i & 63;
        wst[o * 12 + k] = wspan[i];
    }
    if (tid < C_) {
        float inv_n = 1.f / (float)NPIX;
        float mu  = stats[tid] * inv_n;
        float var = stats[C_ + tid] * inv_n - mu * mu;
        float is  = rsqrtf(var + 1e-5f);
        float a   = gamma[tid] * is;
        a_s[tid] = a;
        c_s[tid] = beta[tid] - mu * a;
    }

    int blk = blockIdx.x;
    int b = blk >> 6, t = blk & 63;
    int h0 = (t >> 3) << 4, w0 = (t & 7) << 4;
    int ty = tid >> 4, tx = tid & 15;
    int pix = ((h0 + ty) << 7) + (w0 + tx);
    int pid = (b << 14) + pix;
    size_t base_b = ((size_t)b * C_) << 14;

    // staging geometry, group-independent (item idx = tid + 256k):
    // xh plane addr == idx; global off = (pp<<15) + (gh<<7) + gw  (+ g<<17 + c-pair)
    int gofs[6];
#pragma unroll
    for (int k = 0; k < 6; ++k) {
        int idx = tid + (k << 8);
        int pp  = idx / 324;
        int pos = idx - pp * 324;
        int ly  = pos / 18, lx = pos - ly * 18;
        int gh  = h0 + ly - 1, gw = w0 + lx - 1;
        bool ok = (idx < 1296) && ((unsigned)gh < 128u) && ((unsigned)gw < 128u);
        gofs[k] = ok ? ((pp << 15) + (gh << 7) + gw) : -1;
    }

    float v0[6], v1[6];
    // issue group-0 loads
#pragma unroll
    for (int k = 0; k < 6; ++k) {
        v0[k] = (gofs[k] >= 0) ? x[base_b + gofs[k]] : 0.f;
        v1[k] = (gofs[k] >= 0) ? x[base_b + gofs[k] + HW] : 0.f;
    }

    __syncthreads();   // wst/a_s/c_s ready (group-0 loads in flight)

    // kern[9]: stream r (overlaps group-0 load latency)
    float kern[9];
#pragma unroll
    for (int k = 0; k < 9; ++k) kern[k] = bspan[k];
    const uint4* rp = (const uint4*)(rb + ((size_t)pid << 6));
#pragma unroll
    for (int jj = 0; jj < 8; ++jj) {
        uint4 v = rp[jj];
        const unsigned* u = (const unsigned*)&v;
#pragma unroll
        for (int e = 0; e < 4; ++e) {
            int o = jj * 8 + e * 2;
            float lo = __builtin_bit_cast(float, u[e] << 16);
            float hi = __builtin_bit_cast(float, u[e] & 0xffff0000u);
            float rn0 = fmaxf(a_s[o] * lo + c_s[o], 0.f);
            float rn1 = fmaxf(a_s[o + 1] * hi + c_s[o + 1], 0.f);
            const float* wo0 = &wst[o * 12];
            const float* wo1 = &wst[(o + 1) * 12];
#pragma unroll
            for (int k = 0; k < 9; ++k)
                kern[k] += wo0[k] * rn0 + wo1[k] * rn1;
        }
    }

    // write group 0, issue group-1 loads
#pragma unroll
    for (int k = 0; k < 5; ++k)
        xh[0][tid + (k << 8)] = (unsigned)f2bf(v0[k]) | ((unsigned)f2bf(v1[k]) << 16);
    if (tid < 16)
        xh[0][tid + 1280] = (unsigned)f2bf(v0[5]) | ((unsigned)f2bf(v1[5]) << 16);
#pragma unroll
    for (int k = 0; k < 6; ++k) {
        v0[k] = (gofs[k] >= 0) ? x[base_b + (1 << 17) + gofs[k]] : 0.f;
        v1[k] = (gofs[k] >= 0) ? x[base_b + (1 << 17) + gofs[k] + HW] : 0.f;
    }
    __syncthreads();

    int hrow = ty * 18 + tx;   // halo base for this thread's pixel
#pragma unroll 1
    for (int g = 0; g < 8; ++g) {
        const unsigned* xc = &xh[g & 1][0];
        unsigned pk[4];
#pragma unroll
        for (int cp = 0; cp < 4; ++cp) {
            const unsigned* xp2 = xc + cp * 324;
            float acc0 = 0.f, acc1 = 0.f;
#pragma unroll
            for (int i = 0; i < 3; ++i)
#pragma unroll
                for (int j = 0; j < 3; ++j) {
                    unsigned v = xp2[hrow + i * 18 + j];
                    float kv = kern[i * 3 + j];
                    acc0 += kv * __builtin_bit_cast(float, v << 16);
                    acc1 += kv * __builtin_bit_cast(float, v & 0xffff0000u);
                }
            pk[cp] = (unsigned)f2bf(softplus_fast(acc0))
                   | ((unsigned)f2bf(softplus_fast(acc1)) << 16);
        }
        *(uint4*)&zs[(tid << 5) + ((g ^ (tid & 7)) << 2)] = *(uint4*)pk;

        if (g < 7) {
            // write group g+1 (loads issued last iter; vmcnt waits here)
            unsigned* xn = &xh[(g + 1) & 1][0];
#pragma unroll
            for (int k = 0; k < 5; ++k)
                xn[tid + (k << 8)] = (unsigned)f2bf(v0[k]) | ((unsigned)f2bf(v1[k]) << 16);
            if (tid < 16)
                xn[tid + 1280] = (unsigned)f2bf(v0[5]) | ((unsigned)f2bf(v1[5]) << 16);
            if (g < 6) {
                // issue group g+2 loads
                size_t cb2 = base_b + ((size_t)(g + 2) << 17);
#pragma unroll
                for (int k = 0; k < 6; ++k) {
                    v0[k] = (gofs[k] >= 0) ? x[cb2 + gofs[k]] : 0.f;
                    v1[k] = (gofs[k] >= 0) ? x[cb2 + gofs[k] + HW] : 0.f;
                }
            }
            __syncthreads();
        }
    }

    // flush own 128B z row (own-thread LDS rows: no barrier needed)
    uint4* zp = (uint4*)(zb + ((size_t)pid << 6));
#pragma unroll
    for (int k = 0; k < 8; ++k)
        zp[k] = *(const uint4*)&zs[(tid << 5) + ((k ^ (tid & 7)) << 2)];
}

// K4: dense 3x3 conv 64->64 via implicit-GEMM MFMA + bias + softplus.
__global__ __launch_bounds__(256) void k4_mfma(
    const unsigned short* __restrict__ zb, const unsigned short* __restrict__ wtr,
    const float* __restrict__ b2, float* __restrict__ out)
{
    __shared__ unsigned short zt[324 * 64];   // 41,472 B, chunk-swizzled
    int tid = threadIdx.x;
    int blk = blockIdx.x;
    int b = blk >> 6;
    int t = blk & 63;
    int h0 = (t >> 3) << 4;
    int w0 = (t & 7) << 4;

    for (int idx = tid; idx < 324 * 8; idx += 256) {
        int p  = idx >> 3;
        int cg = idx & 7;
        int py = p / 18, px = p - py * 18;
        int gh = h0 + py - 1, gw = w0 + px - 1;
        uint4 v = make_uint4(0u, 0u, 0u, 0u);
        if ((unsigned)gh < 128u && (unsigned)gw < 128u)
            v = *(const uint4*)(zb + (((size_t)((b << 14) + (gh << 7) + gw)) << 6) + (cg << 3));
        *(uint4*)&zt[(p << 6) + ((cg ^ (p & 7)) << 3)] = v;
    }

    int wid  = tid >> 6, lane = tid & 63;
    int nl   = lane & 15;
    int kg   = lane >> 4;

    short8 wf[18];
    const short8* wp = (const short8*)wtr;
#pragma unroll
    for (int f = 0; f < 18; ++f)
        wf[f] = wp[(size_t)(wid * 18 + f) * 64 + lane];

    f32x4 acc[16];
#pragma unroll
    for (int nt = 0; nt < 16; ++nt) acc[nt] = (f32x4){0.f, 0.f, 0.f, 0.f};

    __syncthreads();

#pragma unroll
    for (int y = 0; y < 18; ++y) {
        short8 bf[6];
#pragma unroll
        for (int j = 0; j < 3; ++j)
#pragma unroll
            for (int ch = 0; ch < 2; ++ch) {
                int p  = y * 18 + j + nl;
                int cg = ch * 4 + kg;
                bf[j * 2 + ch] = *(const short8*)&zt[(p << 6) + ((cg ^ (p & 7)) << 3)];
            }
#pragma unroll
        for (int i = 0; i < 3; ++i) {
            int nt = y - i;
            if (nt >= 0 && nt < 16) {
#pragma unroll
                for (int j = 0; j < 3; ++j)
#pragma unroll
                    for (int ch = 0; ch < 2; ++ch)
                        acc[nt] = __builtin_amdgcn_mfma_f32_16x16x32_bf16(
                            wf[(i * 3 + j) * 2 + ch], bf[j * 2 + ch], acc[nt], 0, 0, 0);
            }
        }
    }

    float bias[4];
#pragma unroll
    for (int r = 0; r < 4; ++r) bias[r] = b2[(wid << 4) + (kg << 2) + r];

    size_t ob = ((size_t)b) << 20;
#pragma unroll
    for (int nt = 0; nt < 16; ++nt) {
        int h = h0 + nt;
#pragma unroll
        for (int r = 0; r < 4; ++r) {
            int o = (wid << 4) + (kg << 2) + r;
            float v = acc[nt][r] + bias[r];
            out[ob + ((size_t)o << 14) + (h << 7) + w0 + nl] = softplus_fast(v);
        }
    }
}

extern "C" void kernel_launch(void* const* d_in, const int* in_sizes, int n_in,
                              void* d_out, int out_size, void* d_ws, size_t ws_size,
                              hipStream_t stream)
{
    const float* x   = (const float*)d_in[0];
    const float* wr  = (const float*)d_in[1];
    const float* br  = (const float*)d_in[2];
    const float* gam = (const float*)d_in[3];
    const float* bet = (const float*)d_in[4];
    const float* wsp = (const float*)d_in[5];
    const float* bsp = (const float*)d_in[6];
    const float* w2  = (const float*)d_in[7];
    const float* b2  = (const float*)d_in[8];
    float* out = (float*)d_out;

    // ws layout: zb bf16[NPIX*64] | wtr bf16[4608*8] | wtr1 bf16[512*8] | stats f32[128]
    unsigned short* zb   = (unsigned short*)d_ws;
    unsigned short* wtr  = zb + (size_t)NPIX * C_;
    unsigned short* wtr1 = wtr + 4608 * 8;
    float* stats = (float*)(wtr1 + 512 * 8);

    // rb: bf16 pixel-major r in d_out scratch; fully consumed before k4.
    unsigned short* rb = (unsigned short*)d_out;

    hipMemsetAsync(stats, 0, 128 * sizeof(float), stream);
    k0_wtr<<<18, 256, 0, stream>>>(w2, wr, wtr, wtr1);
    k1_mfma<<<NPIX / 256, 256, 0, stream>>>(x, wtr1, br, rb);
    k1b_stats<<<128, 256, 0, stream>>>(rb, stats);
    k3_involution<<<NPIX / 256, 256, 0, stream>>>(x, rb, stats, gam, bet, wsp, bsp, zb);
    k4_mfma<<<NPIX / 256, 256, 0, stream>>>(zb, wtr, b2, out);
}

// Round 8
// 87.711 us; speedup vs baseline: 2.1813x; 2.1813x over previous
//
#include <hip/hip_runtime.h>
#include <math.h>

#define H_ 128
#define W_ 128
#define C_ 64
#define B_ 8
#define HW 16384          // H_*W_
#define NPIX (B_*HW)      // 131072

typedef __attribute__((ext_vector_type(8))) short short8;
typedef __attribute__((ext_vector_type(4))) float f32x4;

__device__ __forceinline__ float softplus_fast(float v) {
    return fmaxf(v, 0.f) + __logf(1.f + __expf(-fabsf(v)));
}

__device__ __forceinline__ unsigned short f2bf(float f) {
    unsigned u = __builtin_bit_cast(unsigned, f);
    unsigned r = (u + 0x7fffu + ((u >> 16) & 1u)) >> 16;
    return (unsigned short)r;
}

// async global->LDS, 16B per lane. LDS dest must be linear: base + lane*16.
__device__ __forceinline__ void gl_lds16(const float* g, float* l) {
    __builtin_amdgcn_global_load_lds(
        (const __attribute__((address_space(1))) void*)g,
        (__attribute__((address_space(3))) void*)l, 16, 0, 0);
}

// K0: (a) w2 [o][c][3][3] -> bf16 A-frags (wtr); (b) w_reduce -> A-frags (wtr1);
//     (c) w_span [9][64] -> 2 A-frags, rows 9..15 zero-padded (wtr2).
__global__ __launch_bounds__(256) void k0_wtr(const float* __restrict__ w2,
                                              const float* __restrict__ wr,
                                              const float* __restrict__ wspan,
                                              unsigned short* __restrict__ wtr,
                                              unsigned short* __restrict__ wtr1,
                                              unsigned short* __restrict__ wtr2)
{
    int t = blockIdx.x * 256 + threadIdx.x;
    if (t < 512) {
        int lane = t & 63, f = t >> 6;
        int mt = f >> 1, kh = f & 1;
        int o  = mt * 16 + (lane & 15);
        int c0 = kh * 32 + ((lane >> 4) << 3);
        uint4 pk;
        unsigned short* pv = (unsigned short*)&pk;
#pragma unroll
        for (int e = 0; e < 8; ++e)
            pv[e] = f2bf(wr[o * C_ + c0 + e]);
        *(uint4*)&wtr1[(size_t)t * 8] = pk;
    } else if (t < 640) {
        int tt = t - 512;
        int lane = tt & 63, kh = tt >> 6;
        int o  = lane & 15;
        int c0 = (kh << 5) + ((lane >> 4) << 3);
        uint4 pk;
        unsigned short* pv = (unsigned short*)&pk;
#pragma unroll
        for (int e = 0; e < 8; ++e)
            pv[e] = (o < 9) ? f2bf(wspan[o * C_ + c0 + e]) : (unsigned short)0;
        *(uint4*)&wtr2[(size_t)tt * 8] = pk;
    }
    if (t >= 4 * 18 * 64) return;
    int lane = t & 63;
    int f    = (t >> 6) % 18;
    int wv   = t / (18 * 64);
    int koff = f >> 1, ch = f & 1;
    int o = wv * 16 + (lane & 15);
    int cb = ch * 32 + ((lane >> 4) << 3);
    uint4 pk;
    unsigned short* pv = (unsigned short*)&pk;
#pragma unroll
    for (int e = 0; e < 8; ++e)
        pv[e] = f2bf(w2[(size_t)o * 576 + (size_t)(cb + e) * 9 + koff]);
    *(uint4*)&wtr[(size_t)t * 8] = pk;
}

// K1: r = W_reduce @ x + b_reduce via MFMA implicit GEMM (unchanged, proven).
__global__ __launch_bounds__(256) void k1_mfma(
    const float* __restrict__ x, const unsigned short* __restrict__ wtr1,
    const float* __restrict__ br, unsigned short* __restrict__ rb)
{
    __shared__ unsigned short xb[256 * 64];   // 32KB, chunk-XOR swizzled
    __shared__ float brs[C_];
    int tid = threadIdx.x;
    int blk = blockIdx.x;
    int pid0 = blk << 8;
    int b    = pid0 >> 14;
    int rem0 = pid0 & (HW - 1);
    const float* xbase = x + (((size_t)b * C_) << 14) + rem0;

    if (tid < C_) brs[tid] = br[tid];

    int p = tid;
#pragma unroll
    for (int m = 0; m < 8; ++m) {
        float tmp[8];
#pragma unroll
        for (int e = 0; e < 8; ++e)
            tmp[e] = xbase[((size_t)(m * 8 + e) << 14) + p];
        unsigned pk[4];
#pragma unroll
        for (int e = 0; e < 4; ++e)
            pk[e] = (unsigned)f2bf(tmp[2 * e]) | ((unsigned)f2bf(tmp[2 * e + 1]) << 16);
        *(uint4*)&xb[(p << 6) + ((m ^ (p & 7)) << 3)] = *(uint4*)pk;
    }

    int wid = tid >> 6, lane = tid & 63;
    int nl  = lane & 15;
    int kg  = lane >> 4;

    short8 af[8];
    const short8* wp = (const short8*)wtr1;
#pragma unroll
    for (int f = 0; f < 8; ++f) af[f] = wp[f * 64 + lane];

    f32x4 acc[4][4];
#pragma unroll
    for (int mt = 0; mt < 4; ++mt)
#pragma unroll
        for (int nt = 0; nt < 4; ++nt) acc[mt][nt] = (f32x4){0.f, 0.f, 0.f, 0.f};

    __syncthreads();

    int nbase = wid << 6;
#pragma unroll
    for (int nt = 0; nt < 4; ++nt) {
        int pp = nbase + (nt << 4) + nl;
#pragma unroll
        for (int kh = 0; kh < 2; ++kh) {
            int m = kh * 4 + kg;
            short8 bf = *(const short8*)&xb[(pp << 6) + ((m ^ (pp & 7)) << 3)];
#pragma unroll
            for (int mt = 0; mt < 4; ++mt)
                acc[mt][nt] = __builtin_amdgcn_mfma_f32_16x16x32_bf16(
                    af[mt * 2 + kh], bf, acc[mt][nt], 0, 0, 0);
        }
    }

    __syncthreads();

#pragma unroll
    for (int mt = 0; mt < 4; ++mt) {
        int c = (mt << 4) + (kg << 2);
        float b0 = brs[c], b1 = brs[c + 1], b2v = brs[c + 2], b3 = brs[c + 3];
        int chunk = c >> 3;
#pragma unroll
        for (int nt = 0; nt < 4; ++nt) {
            int pp = nbase + (nt << 4) + nl;
            f32x4 a = acc[mt][nt];
            unsigned lo = (unsigned)f2bf(a[0] + b0) | ((unsigned)f2bf(a[1] + b1) << 16);
            unsigned hi = (unsigned)f2bf(a[2] + b2v) | ((unsigned)f2bf(a[3] + b3) << 16);
            unsigned* dst = (unsigned*)&xb[(pp << 6) + ((chunk ^ (pp & 7)) << 3) + ((kg & 1) << 2)];
            dst[0] = lo;
            dst[1] = hi;
        }
    }
    __syncthreads();

    uint4* rp = (uint4*)(rb + ((size_t)(pid0 + p) << 6));
#pragma unroll
    for (int m = 0; m < 8; ++m)
        rp[m] = *(const uint4*)&xb[(p << 6) + ((m ^ (p & 7)) << 3)];
}

// K1b: per-channel sum/sumsq over rb (bf16 pixel-major). Unchanged.
__global__ __launch_bounds__(256) void k1b_stats(
    const unsigned short* __restrict__ rb, float* __restrict__ stats)
{
    __shared__ float ls[128];
    int tid = threadIdx.x;
    if (tid < 128) ls[tid] = 0.f;
    __syncthreads();

    int j   = tid & 7;
    int row = (blockIdx.x << 5) + (tid >> 3);
    float s[8] = {0,0,0,0,0,0,0,0}, q[8] = {0,0,0,0,0,0,0,0};
    for (int p = row; p < NPIX; p += (gridDim.x << 5)) {
        uint4 v = *(const uint4*)(rb + ((size_t)p << 6) + (j << 3));
        const unsigned* u = (const unsigned*)&v;
#pragma unroll
        for (int e = 0; e < 4; ++e) {
            float lo = __builtin_bit_cast(float, u[e] << 16);
            float hi = __builtin_bit_cast(float, u[e] & 0xffff0000u);
            s[2*e]   += lo; q[2*e]   += lo * lo;
            s[2*e+1] += hi; q[2*e+1] += hi * hi;
        }
    }
#pragma unroll
    for (int e = 0; e < 8; ++e) {
#pragma unroll
        for (int m = 8; m <= 32; m <<= 1) {
            s[e] += __shfl_xor(s[e], m, 64);
            q[e] += __shfl_xor(q[e], m, 64);
        }
    }
    int lane = tid & 63;
    if (lane < 8) {
#pragma unroll
        for (int e = 0; e < 8; ++e) {
            atomicAdd(&ls[lane * 8 + e], s[e]);
            atomicAdd(&ls[64 + lane * 8 + e], q[e]);
        }
    }
    __syncthreads();
    if (tid < 128) atomicAdd(&stats[tid], ls[tid]);
}

// K3 v3: halo staged f32 via global_load_lds (dbuf, depth-1 pipeline, OOB
// items read a zeroed global word); kern[9] via MFMA (w_spanT frags x rn
// B-frags, K1 conventions) + LDS bounce; involution; z via zs row flush.
__global__ __launch_bounds__(256) void k3_involution(
    const float* __restrict__ x, const unsigned short* __restrict__ rb,
    const float* __restrict__ stats, const float* __restrict__ gamma,
    const float* __restrict__ beta, const unsigned short* __restrict__ wtr2,
    const float* __restrict__ bspan, unsigned short* __restrict__ zb)
{
    // halo: [8ch][18 rows][24 dwords] f32, rows cover gw in [w0-4, w0+20)
    __shared__ float xh0[3456], xh1[3456];      // 13.8KB x2
    __shared__ unsigned zs[256 * 32];           // 32KB (first 9.2KB reused as kern bounce)
    __shared__ float a_s[C_], c_s[C_];

    int tid = threadIdx.x;
    if (tid < C_) {
        float inv_n = 1.f / (float)NPIX;
        float mu  = stats[tid] * inv_n;
        float var = stats[C_ + tid] * inv_n - mu * mu;
        float is  = rsqrtf(var + 1e-5f);
        float a   = gamma[tid] * is;
        a_s[tid] = a;
        c_s[tid] = beta[tid] - mu * a;
    }

    int blk = blockIdx.x;
    int b = blk >> 6, t = blk & 63;
    int h0 = (t >> 3) << 4, w0 = (t & 7) << 4;
    int ty = tid >> 4, tx = tid & 15;
    int pix = ((h0 + ty) << 7) + (w0 + tx);
    int pid = (b << 14) + pix;
    const float* xb_ = x + (((size_t)b * C_) << 14);
    const float* zgz = stats + 128;   // zeroed 16B region

    // per-thread DMA items: item = k*256+tid -> (c, row, ii); 864 items/group
    int goff[4];
#pragma unroll
    for (int k = 0; k < 4; ++k) {
        int item = (k << 8) + tid;
        int c    = item / 108;
        int rem  = item - c * 108;
        int row  = rem / 6;
        int ii   = rem - row * 6;
        int gh   = h0 + row - 1;
        int gw0  = w0 - 4 + (ii << 2);
        bool ok = (item < 864) && ((unsigned)gh < 128u) && ((unsigned)gw0 < 128u);
        goff[k] = ok ? ((c << 14) + (gh << 7) + gw0) : -1;
    }

    auto stage = [&](int g, float* buf) {
#pragma unroll
        for (int k = 0; k < 4; ++k) {
            if (k < 3 || tid < 96) {
                int item = (k << 8) + tid;
                const float* src = (goff[k] >= 0) ? (xb_ + (g << 17) + goff[k]) : zgz;
                gl_lds16(src, buf + (item << 2));
            }
        }
    };

    int lane = tid & 63;
    int w_  = tid >> 6;
    int nl  = lane & 15;
    int kg  = lane >> 4;
    short8 af0 = ((const short8*)wtr2)[lane];
    short8 af1 = ((const short8*)wtr2)[64 + lane];

    stage(0, xh0);
    __syncthreads();               // a_s/c_s ready; stage0 landed
    stage(1, xh1);                 // flies under the whole kern phase

    // ---- kern[9] via MFMA ----
    float aa[2][8], cc[2][8];
#pragma unroll
    for (int kh = 0; kh < 2; ++kh) {
        int cb = (kh << 5) + (kg << 3);
#pragma unroll
        for (int e = 0; e < 8; ++e) { aa[kh][e] = a_s[cb + e]; cc[kh][e] = c_s[cb + e]; }
    }

    f32x4 acc9[4];
#pragma unroll
    for (int nt = 0; nt < 4; ++nt) acc9[nt] = (f32x4){0.f, 0.f, 0.f, 0.f};

#pragma unroll
    for (int nt = 0; nt < 4; ++nt) {
        int prow = h0 + (w_ << 2) + nt;
        int pid2 = (b << 14) + (prow << 7) + w0 + nl;
#pragma unroll
        for (int kh = 0; kh < 2; ++kh) {
            uint4 rv = *(const uint4*)(rb + ((size_t)pid2 << 6) + (kh << 5) + (kg << 3));
            const unsigned* ru = (const unsigned*)&rv;
            unsigned po[4];
#pragma unroll
            for (int e2 = 0; e2 < 4; ++e2) {
                float lo = __builtin_bit_cast(float, ru[e2] << 16);
                float hi = __builtin_bit_cast(float, ru[e2] & 0xffff0000u);
                float r0 = fmaxf(aa[kh][2 * e2]     * lo + cc[kh][2 * e2],     0.f);
                float r1 = fmaxf(aa[kh][2 * e2 + 1] * hi + cc[kh][2 * e2 + 1], 0.f);
                po[e2] = (unsigned)f2bf(r0) | ((unsigned)f2bf(r1) << 16);
            }
            short8 bfrag = __builtin_bit_cast(short8, *(uint4*)po);
            acc9[nt] = __builtin_amdgcn_mfma_f32_16x16x32_bf16(
                kh ? af1 : af0, bfrag, acc9[nt], 0, 0, 0);
        }
    }

    // bounce: C row (kg*4+e) = kern index, col nl = pixel; -> kern_lds[px][9]
    float* kl = (float*)zs;
#pragma unroll
    for (int nt = 0; nt < 4; ++nt) {
        int px = (w_ << 6) + (nt << 4) + nl;
#pragma unroll
        for (int e = 0; e < 4; ++e) {
            int rr = (kg << 2) + e;
            if (rr < 9) kl[px * 9 + rr] = acc9[nt][e];
        }
    }
    __syncthreads();
    float kern[9];
#pragma unroll
    for (int k = 0; k < 9; ++k) kern[k] = kl[tid * 9 + k] + bspan[k];
    __syncthreads();               // bounce reads done before zs reuse

    // ---- involution, 8 groups of 8 channels, depth-1 DMA pipeline ----
#pragma unroll 1
    for (int g = 0; g < 8; ++g) {
        if (g >= 1 && g < 7) stage(g + 1, (g & 1) ? xh0 : xh1);
        const float* xf = (g & 1) ? xh1 : xh0;
        unsigned pk[4];
#pragma unroll
        for (int cp = 0; cp < 4; ++cp) {
            const float* p0 = xf + (cp * 2) * 432 + ty * 24 + tx + 3;
            const float* p1 = p0 + 432;
            float acc0 = 0.f, acc1 = 0.f;
#pragma unroll
            for (int i = 0; i < 3; ++i)
#pragma unroll
                for (int j = 0; j < 3; ++j) {
                    float kv = kern[i * 3 + j];
                    acc0 += kv * p0[i * 24 + j];
                    acc1 += kv * p1[i * 24 + j];
                }
            pk[cp] = (unsigned)f2bf(softplus_fast(acc0))
                   | ((unsigned)f2bf(softplus_fast(acc1)) << 16);
        }
        *(uint4*)&zs[(tid << 5) + ((g ^ (tid & 7)) << 2)] = *(uint4*)pk;
        if (g < 7) __syncthreads();
    }

    // flush own 128B z row (own-thread LDS rows: no barrier needed)
    uint4* zp = (uint4*)(zb + ((size_t)pid << 6));
#pragma unroll
    for (int k = 0; k < 8; ++k)
        zp[k] = *(const uint4*)&zs[(tid << 5) + ((k ^ (tid & 7)) << 2)];
}

// K4: dense 3x3 conv 64->64 via implicit-GEMM MFMA + bias + softplus.
__global__ __launch_bounds__(256) void k4_mfma(
    const unsigned short* __restrict__ zb, const unsigned short* __restrict__ wtr,
    const float* __restrict__ b2, float* __restrict__ out)
{
    __shared__ unsigned short zt[324 * 64];   // 41,472 B, chunk-swizzled
    int tid = threadIdx.x;
    int blk = blockIdx.x;
    int b = blk >> 6;
    int t = blk & 63;
    int h0 = (t >> 3) << 4;
    int w0 = (t & 7) << 4;

    for (int idx = tid; idx < 324 * 8; idx += 256) {
        int p  = idx >> 3;
        int cg = idx & 7;
        int py = p / 18, px = p - py * 18;
        int gh = h0 + py - 1, gw = w0 + px - 1;
        uint4 v = make_uint4(0u, 0u, 0u, 0u);
        if ((unsigned)gh < 128u && (unsigned)gw < 128u)
            v = *(const uint4*)(zb + (((size_t)((b << 14) + (gh << 7) + gw)) << 6) + (cg << 3));
        *(uint4*)&zt[(p << 6) + ((cg ^ (p & 7)) << 3)] = v;
    }

    int wid  = tid >> 6, lane = tid & 63;
    int nl   = lane & 15;
    int kg   = lane >> 4;

    short8 wf[18];
    const short8* wp = (const short8*)wtr;
#pragma unroll
    for (int f = 0; f < 18; ++f)
        wf[f] = wp[(size_t)(wid * 18 + f) * 64 + lane];

    f32x4 acc[16];
#pragma unroll
    for (int nt = 0; nt < 16; ++nt) acc[nt] = (f32x4){0.f, 0.f, 0.f, 0.f};

    __syncthreads();

#pragma unroll
    for (int y = 0; y < 18; ++y) {
        short8 bf[6];
#pragma unroll
        for (int j = 0; j < 3; ++j)
#pragma unroll
            for (int ch = 0; ch < 2; ++ch) {
                int p  = y * 18 + j + nl;
                int cg = ch * 4 + kg;
                bf[j * 2 + ch] = *(const short8*)&zt[(p << 6) + ((cg ^ (p & 7)) << 3)];
            }
#pragma unroll
        for (int i = 0; i < 3; ++i) {
            int nt = y - i;
            if (nt >= 0 && nt < 16) {
#pragma unroll
                for (int j = 0; j < 3; ++j)
#pragma unroll
                    for (int ch = 0; ch < 2; ++ch)
                        acc[nt] = __builtin_amdgcn_mfma_f32_16x16x32_bf16(
                            wf[(i * 3 + j) * 2 + ch], bf[j * 2 + ch], acc[nt], 0, 0, 0);
            }
        }
    }

    float bias[4];
#pragma unroll
    for (int r = 0; r < 4; ++r) bias[r] = b2[(wid << 4) + (kg << 2) + r];

    size_t ob = ((size_t)b) << 20;
#pragma unroll
    for (int nt = 0; nt < 16; ++nt) {
        int h = h0 + nt;
#pragma unroll
        for (int r = 0; r < 4; ++r) {
            int o = (wid << 4) + (kg << 2) + r;
            float v = acc[nt][r] + bias[r];
            out[ob + ((size_t)o << 14) + (h << 7) + w0 + nl] = softplus_fast(v);
        }
    }
}

extern "C" void kernel_launch(void* const* d_in, const int* in_sizes, int n_in,
                              void* d_out, int out_size, void* d_ws, size_t ws_size,
                              hipStream_t stream)
{
    const float* x   = (const float*)d_in[0];
    const float* wr  = (const float*)d_in[1];
    const float* br  = (const float*)d_in[2];
    const float* gam = (const float*)d_in[3];
    const float* bet = (const float*)d_in[4];
    const float* wsp = (const float*)d_in[5];
    const float* bsp = (const float*)d_in[6];
    const float* w2  = (const float*)d_in[7];
    const float* b2  = (const float*)d_in[8];
    float* out = (float*)d_out;

    // ws: zb bf16[NPIX*64] | wtr[4608*8] | wtr1[512*8] | wtr2[128*8] | stats f32[128] | zeros f32[128]
    unsigned short* zb   = (unsigned short*)d_ws;
    unsigned short* wtr  = zb + (size_t)NPIX * C_;
    unsigned short* wtr1 = wtr + 4608 * 8;
    unsigned short* wtr2 = wtr1 + 512 * 8;
    float* stats = (float*)(wtr2 + 128 * 8);

    // rb: bf16 pixel-major r in d_out scratch; fully consumed before k4.
    unsigned short* rb = (unsigned short*)d_out;

    hipMemsetAsync(stats, 0, 1024, stream);   // stats[128] + zeros[128]
    k0_wtr<<<18, 256, 0, stream>>>(w2, wr, wsp, wtr, wtr1, wtr2);
    k1_mfma<<<NPIX / 256, 256, 0, stream>>>(x, wtr1, br, rb);
    k1b_stats<<<128, 256, 0, stream>>>(rb, stats);
    k3_involution<<<NPIX / 256, 256, 0, stream>>>(x, rb, stats, gam, bet, wtr2, bsp, zb);
    k4_mfma<<<NPIX / 256, 256, 0, stream>>>(zb, wtr, b2, out);
}

// Round 9
// 80.843 us; speedup vs baseline: 2.3667x; 1.0850x over previous
//
#include <hip/hip_runtime.h>
#include <math.h>

#define H_ 128
#define W_ 128
#define C_ 64
#define B_ 8
#define HW 16384          // H_*W_
#define NPIX (B_*HW)      // 131072

typedef __attribute__((ext_vector_type(8))) short short8;
typedef __attribute__((ext_vector_type(4))) float f32x4;

__device__ __forceinline__ float softplus_fast(float v) {
    return fmaxf(v, 0.f) + __logf(1.f + __expf(-fabsf(v)));
}

__device__ __forceinline__ unsigned short f2bf(float f) {
    unsigned u = __builtin_bit_cast(unsigned, f);
    unsigned r = (u + 0x7fffu + ((u >> 16) & 1u)) >> 16;
    return (unsigned short)r;
}

// async global->LDS, 16B per lane. LDS dest must be linear: base + lane*16.
__device__ __forceinline__ void gl_lds16(const float* g, float* l) {
    __builtin_amdgcn_global_load_lds(
        (const __attribute__((address_space(1))) void*)g,
        (__attribute__((address_space(3))) void*)l, 16, 0, 0);
}

// K0: (a) w2 -> bf16 A-frags (wtr); (b) w_reduce -> A-frags (wtr1);
//     (c) w_span -> 2 zero-padded A-frags (wtr2); (d) block 0 zeroes
//     stats[128] + zgz[128] (replaces hipMemsetAsync; must run every call).
__global__ __launch_bounds__(256) void k0_wtr(const float* __restrict__ w2,
                                              const float* __restrict__ wr,
                                              const float* __restrict__ wspan,
                                              unsigned short* __restrict__ wtr,
                                              unsigned short* __restrict__ wtr1,
                                              unsigned short* __restrict__ wtr2,
                                              float* __restrict__ stats)
{
    int t = blockIdx.x * 256 + threadIdx.x;
    if (t < 256) stats[t] = 0.f;            // stats[128] + zeros[128]
    if (t < 512) {
        int lane = t & 63, f = t >> 6;
        int mt = f >> 1, kh = f & 1;
        int o  = mt * 16 + (lane & 15);
        int c0 = kh * 32 + ((lane >> 4) << 3);
        uint4 pk;
        unsigned short* pv = (unsigned short*)&pk;
#pragma unroll
        for (int e = 0; e < 8; ++e)
            pv[e] = f2bf(wr[o * C_ + c0 + e]);
        *(uint4*)&wtr1[(size_t)t * 8] = pk;
    } else if (t < 640) {
        int tt = t - 512;
        int lane = tt & 63, kh = tt >> 6;
        int o  = lane & 15;
        int c0 = (kh << 5) + ((lane >> 4) << 3);
        uint4 pk;
        unsigned short* pv = (unsigned short*)&pk;
#pragma unroll
        for (int e = 0; e < 8; ++e)
            pv[e] = (o < 9) ? f2bf(wspan[o * C_ + c0 + e]) : (unsigned short)0;
        *(uint4*)&wtr2[(size_t)tt * 8] = pk;
    }
    if (t >= 4 * 18 * 64) return;
    int lane = t & 63;
    int f    = (t >> 6) % 18;
    int wv   = t / (18 * 64);
    int koff = f >> 1, ch = f & 1;
    int o = wv * 16 + (lane & 15);
    int cb = ch * 32 + ((lane >> 4) << 3);
    uint4 pk;
    unsigned short* pv = (unsigned short*)&pk;
#pragma unroll
    for (int e = 0; e < 8; ++e)
        pv[e] = f2bf(w2[(size_t)o * 576 + (size_t)(cb + e) * 9 + koff]);
    *(uint4*)&wtr[(size_t)t * 8] = pk;
}

// K1: r = W_reduce @ x + b_reduce via MFMA implicit GEMM; BN stats
// (sum/sumsq incl. bias, f32) folded in from the accumulators.
__global__ __launch_bounds__(256) void k1_mfma(
    const float* __restrict__ x, const unsigned short* __restrict__ wtr1,
    const float* __restrict__ br, unsigned short* __restrict__ rb,
    float* __restrict__ stats)
{
    __shared__ unsigned short xb[256 * 64];   // 32KB, chunk-XOR swizzled
    __shared__ float brs[C_];
    __shared__ float ls[128];
    int tid = threadIdx.x;
    int blk = blockIdx.x;
    int pid0 = blk << 8;
    int b    = pid0 >> 14;
    int rem0 = pid0 & (HW - 1);
    const float* xbase = x + (((size_t)b * C_) << 14) + rem0;

    if (tid < C_) brs[tid] = br[tid];
    if (tid < 128) ls[tid] = 0.f;

    int p = tid;
#pragma unroll
    for (int m = 0; m < 8; ++m) {
        float tmp[8];
#pragma unroll
        for (int e = 0; e < 8; ++e)
            tmp[e] = xbase[((size_t)(m * 8 + e) << 14) + p];
        unsigned pk[4];
#pragma unroll
        for (int e = 0; e < 4; ++e)
            pk[e] = (unsigned)f2bf(tmp[2 * e]) | ((unsigned)f2bf(tmp[2 * e + 1]) << 16);
        *(uint4*)&xb[(p << 6) + ((m ^ (p & 7)) << 3)] = *(uint4*)pk;
    }

    int wid = tid >> 6, lane = tid & 63;
    int nl  = lane & 15;
    int kg  = lane >> 4;

    short8 af[8];
    const short8* wp = (const short8*)wtr1;
#pragma unroll
    for (int f = 0; f < 8; ++f) af[f] = wp[f * 64 + lane];

    f32x4 acc[4][4];
#pragma unroll
    for (int mt = 0; mt < 4; ++mt)
#pragma unroll
        for (int nt = 0; nt < 4; ++nt) acc[mt][nt] = (f32x4){0.f, 0.f, 0.f, 0.f};

    __syncthreads();

    int nbase = wid << 6;
#pragma unroll
    for (int nt = 0; nt < 4; ++nt) {
        int pp = nbase + (nt << 4) + nl;
#pragma unroll
        for (int kh = 0; kh < 2; ++kh) {
            int m = kh * 4 + kg;
            short8 bf = *(const short8*)&xb[(pp << 6) + ((m ^ (pp & 7)) << 3)];
#pragma unroll
            for (int mt = 0; mt < 4; ++mt)
                acc[mt][nt] = __builtin_amdgcn_mfma_f32_16x16x32_bf16(
                    af[mt * 2 + kh], bf, acc[mt][nt], 0, 0, 0);
        }
    }

    __syncthreads();

    // epilogue: bias + pack to xb + per-channel stats accumulation
    float s_[16], q_[16];
#pragma unroll
    for (int i = 0; i < 16; ++i) { s_[i] = 0.f; q_[i] = 0.f; }

#pragma unroll
    for (int mt = 0; mt < 4; ++mt) {
        int c = (mt << 4) + (kg << 2);
        float b0 = brs[c], b1 = brs[c + 1], b2v = brs[c + 2], b3 = brs[c + 3];
        int chunk = c >> 3;
#pragma unroll
        for (int nt = 0; nt < 4; ++nt) {
            int pp = nbase + (nt << 4) + nl;
            f32x4 a = acc[mt][nt];
            float v0 = a[0] + b0, v1 = a[1] + b1, v2 = a[2] + b2v, v3 = a[3] + b3;
            s_[mt * 4 + 0] += v0; q_[mt * 4 + 0] += v0 * v0;
            s_[mt * 4 + 1] += v1; q_[mt * 4 + 1] += v1 * v1;
            s_[mt * 4 + 2] += v2; q_[mt * 4 + 2] += v2 * v2;
            s_[mt * 4 + 3] += v3; q_[mt * 4 + 3] += v3 * v3;
            unsigned lo = (unsigned)f2bf(v0) | ((unsigned)f2bf(v1) << 16);
            unsigned hi = (unsigned)f2bf(v2) | ((unsigned)f2bf(v3) << 16);
            unsigned* dst = (unsigned*)&xb[(pp << 6) + ((chunk ^ (pp & 7)) << 3) + ((kg & 1) << 2)];
            dst[0] = lo;
            dst[1] = hi;
        }
    }

    // reduce stats across the 16 pixel-lanes (nl), then LDS, then global
#pragma unroll
    for (int i = 0; i < 16; ++i) {
#pragma unroll
        for (int m = 1; m <= 8; m <<= 1) {
            s_[i] += __shfl_xor(s_[i], m, 64);
            q_[i] += __shfl_xor(q_[i], m, 64);
        }
    }
    if (nl == 0) {
#pragma unroll
        for (int i = 0; i < 16; ++i) {
            int c = ((i >> 2) << 4) + (kg << 2) + (i & 3);
            atomicAdd(&ls[c], s_[i]);
            atomicAdd(&ls[64 + c], q_[i]);
        }
    }
    __syncthreads();
    if (tid < 128) atomicAdd(&stats[tid], ls[tid]);

    uint4* rp = (uint4*)(rb + ((size_t)(pid0 + p) << 6));
#pragma unroll
    for (int m = 0; m < 8; ++m)
        rp[m] = *(const uint4*)&xb[(p << 6) + ((m ^ (p & 7)) << 3)];
}

// K3 v3: halo staged f32 via global_load_lds (dbuf, depth-1 pipeline, OOB
// items read a zeroed global word); kern[9] via MFMA + LDS bounce;
// involution; z via zs row flush. Unchanged from round 7 (passed).
__global__ __launch_bounds__(256) void k3_involution(
    const float* __restrict__ x, const unsigned short* __restrict__ rb,
    const float* __restrict__ stats, const float* __restrict__ gamma,
    const float* __restrict__ beta, const unsigned short* __restrict__ wtr2,
    const float* __restrict__ bspan, unsigned short* __restrict__ zb)
{
    __shared__ float xh0[3456], xh1[3456];      // [8ch][18][24] f32, dbuf
    __shared__ unsigned zs[256 * 32];           // 32KB (first 9.2KB = kern bounce)
    __shared__ float a_s[C_], c_s[C_];

    int tid = threadIdx.x;
    if (tid < C_) {
        float inv_n = 1.f / (float)NPIX;
        float mu  = stats[tid] * inv_n;
        float var = stats[C_ + tid] * inv_n - mu * mu;
        float is  = rsqrtf(var + 1e-5f);
        float a   = gamma[tid] * is;
        a_s[tid] = a;
        c_s[tid] = beta[tid] - mu * a;
    }

    int blk = blockIdx.x;
    int b = blk >> 6, t = blk & 63;
    int h0 = (t >> 3) << 4, w0 = (t & 7) << 4;
    int ty = tid >> 4, tx = tid & 15;
    int pix = ((h0 + ty) << 7) + (w0 + tx);
    int pid = (b << 14) + pix;
    const float* xb_ = x + (((size_t)b * C_) << 14);
    const float* zgz = stats + 128;   // zeroed 16B region

    int goff[4];
#pragma unroll
    for (int k = 0; k < 4; ++k) {
        int item = (k << 8) + tid;
        int c    = item / 108;
        int rem  = item - c * 108;
        int row  = rem / 6;
        int ii   = rem - row * 6;
        int gh   = h0 + row - 1;
        int gw0  = w0 - 4 + (ii << 2);
        bool ok = (item < 864) && ((unsigned)gh < 128u) && ((unsigned)gw0 < 128u);
        goff[k] = ok ? ((c << 14) + (gh << 7) + gw0) : -1;
    }

    auto stage = [&](int g, float* buf) {
#pragma unroll
        for (int k = 0; k < 4; ++k) {
            if (k < 3 || tid < 96) {
                int item = (k << 8) + tid;
                const float* src = (goff[k] >= 0) ? (xb_ + (g << 17) + goff[k]) : zgz;
                gl_lds16(src, buf + (item << 2));
            }
        }
    };

    int lane = tid & 63;
    int w_  = tid >> 6;
    int nl  = lane & 15;
    int kg  = lane >> 4;
    short8 af0 = ((const short8*)wtr2)[lane];
    short8 af1 = ((const short8*)wtr2)[64 + lane];

    stage(0, xh0);
    __syncthreads();               // a_s/c_s ready; stage0 landed
    stage(1, xh1);                 // flies under the whole kern phase

    // ---- kern[9] via MFMA ----
    float aa[2][8], cc[2][8];
#pragma unroll
    for (int kh = 0; kh < 2; ++kh) {
        int cb = (kh << 5) + (kg << 3);
#pragma unroll
        for (int e = 0; e < 8; ++e) { aa[kh][e] = a_s[cb + e]; cc[kh][e] = c_s[cb + e]; }
    }

    f32x4 acc9[4];
#pragma unroll
    for (int nt = 0; nt < 4; ++nt) acc9[nt] = (f32x4){0.f, 0.f, 0.f, 0.f};

#pragma unroll
    for (int nt = 0; nt < 4; ++nt) {
        int prow = h0 + (w_ << 2) + nt;
        int pid2 = (b << 14) + (prow << 7) + w0 + nl;
#pragma unroll
        for (int kh = 0; kh < 2; ++kh) {
            uint4 rv = *(const uint4*)(rb + ((size_t)pid2 << 6) + (kh << 5) + (kg << 3));
            const unsigned* ru = (const unsigned*)&rv;
            unsigned po[4];
#pragma unroll
            for (int e2 = 0; e2 < 4; ++e2) {
                float lo = __builtin_bit_cast(float, ru[e2] << 16);
                float hi = __builtin_bit_cast(float, ru[e2] & 0xffff0000u);
                float r0 = fmaxf(aa[kh][2 * e2]     * lo + cc[kh][2 * e2],     0.f);
                float r1 = fmaxf(aa[kh][2 * e2 + 1] * hi + cc[kh][2 * e2 + 1], 0.f);
                po[e2] = (unsigned)f2bf(r0) | ((unsigned)f2bf(r1) << 16);
            }
            short8 bfrag = __builtin_bit_cast(short8, *(uint4*)po);
            acc9[nt] = __builtin_amdgcn_mfma_f32_16x16x32_bf16(
                kh ? af1 : af0, bfrag, acc9[nt], 0, 0, 0);
        }
    }

    float* kl = (float*)zs;
#pragma unroll
    for (int nt = 0; nt < 4; ++nt) {
        int px = (w_ << 6) + (nt << 4) + nl;
#pragma unroll
        for (int e = 0; e < 4; ++e) {
            int rr = (kg << 2) + e;
            if (rr < 9) kl[px * 9 + rr] = acc9[nt][e];
        }
    }
    __syncthreads();
    float kern[9];
#pragma unroll
    for (int k = 0; k < 9; ++k) kern[k] = kl[tid * 9 + k] + bspan[k];
    __syncthreads();               // bounce reads done before zs reuse

    // ---- involution, 8 groups of 8 channels, depth-1 DMA pipeline ----
#pragma unroll 1
    for (int g = 0; g < 8; ++g) {
        if (g >= 1 && g < 7) stage(g + 1, (g & 1) ? xh0 : xh1);
        const float* xf = (g & 1) ? xh1 : xh0;
        unsigned pk[4];
#pragma unroll
        for (int cp = 0; cp < 4; ++cp) {
            const float* p0 = xf + (cp * 2) * 432 + ty * 24 + tx + 3;
            const float* p1 = p0 + 432;
            float acc0 = 0.f, acc1 = 0.f;
#pragma unroll
            for (int i = 0; i < 3; ++i)
#pragma unroll
                for (int j = 0; j < 3; ++j) {
                    float kv = kern[i * 3 + j];
                    acc0 += kv * p0[i * 24 + j];
                    acc1 += kv * p1[i * 24 + j];
                }
            pk[cp] = (unsigned)f2bf(softplus_fast(acc0))
                   | ((unsigned)f2bf(softplus_fast(acc1)) << 16);
        }
        *(uint4*)&zs[(tid << 5) + ((g ^ (tid & 7)) << 2)] = *(uint4*)pk;
        if (g < 7) __syncthreads();
    }

    uint4* zp = (uint4*)(zb + ((size_t)pid << 6));
#pragma unroll
    for (int k = 0; k < 8; ++k)
        zp[k] = *(const uint4*)&zs[(tid << 5) + ((k ^ (tid & 7)) << 2)];
}

// K4: dense 3x3 conv 64->64 via implicit-GEMM MFMA + bias + softplus.
__global__ __launch_bounds__(256) void k4_mfma(
    const unsigned short* __restrict__ zb, const unsigned short* __restrict__ wtr,
    const float* __restrict__ b2, float* __restrict__ out)
{
    __shared__ unsigned short zt[324 * 64];   // 41,472 B, chunk-swizzled
    int tid = threadIdx.x;
    int blk = blockIdx.x;
    int b = blk >> 6;
    int t = blk & 63;
    int h0 = (t >> 3) << 4;
    int w0 = (t & 7) << 4;

    for (int idx = tid; idx < 324 * 8; idx += 256) {
        int p  = idx >> 3;
        int cg = idx & 7;
        int py = p / 18, px = p - py * 18;
        int gh = h0 + py - 1, gw = w0 + px - 1;
        uint4 v = make_uint4(0u, 0u, 0u, 0u);
        if ((unsigned)gh < 128u && (unsigned)gw < 128u)
            v = *(const uint4*)(zb + (((size_t)((b << 14) + (gh << 7) + gw)) << 6) + (cg << 3));
        *(uint4*)&zt[(p << 6) + ((cg ^ (p & 7)) << 3)] = v;
    }

    int wid  = tid >> 6, lane = tid & 63;
    int nl   = lane & 15;
    int kg   = lane >> 4;

    short8 wf[18];
    const short8* wp = (const short8*)wtr;
#pragma unroll
    for (int f = 0; f < 18; ++f)
        wf[f] = wp[(size_t)(wid * 18 + f) * 64 + lane];

    f32x4 acc[16];
#pragma unroll
    for (int nt = 0; nt < 16; ++nt) acc[nt] = (f32x4){0.f, 0.f, 0.f, 0.f};

    __syncthreads();

#pragma unroll
    for (int y = 0; y < 18; ++y) {
        short8 bf[6];
#pragma unroll
        for (int j = 0; j < 3; ++j)
#pragma unroll
            for (int ch = 0; ch < 2; ++ch) {
                int p  = y * 18 + j + nl;
                int cg = ch * 4 + kg;
                bf[j * 2 + ch] = *(const short8*)&zt[(p << 6) + ((cg ^ (p & 7)) << 3)];
            }
#pragma unroll
        for (int i = 0; i < 3; ++i) {
            int nt = y - i;
            if (nt >= 0 && nt < 16) {
#pragma unroll
                for (int j = 0; j < 3; ++j)
#pragma unroll
                    for (int ch = 0; ch < 2; ++ch)
                        acc[nt] = __builtin_amdgcn_mfma_f32_16x16x32_bf16(
                            wf[(i * 3 + j) * 2 + ch], bf[j * 2 + ch], acc[nt], 0, 0, 0);
            }
        }
    }

    float bias[4];
#pragma unroll
    for (int r = 0; r < 4; ++r) bias[r] = b2[(wid << 4) + (kg << 2) + r];

    size_t ob = ((size_t)b) << 20;
#pragma unroll
    for (int nt = 0; nt < 16; ++nt) {
        int h = h0 + nt;
#pragma unroll
        for (int r = 0; r < 4; ++r) {
            int o = (wid << 4) + (kg << 2) + r;
            float v = acc[nt][r] + bias[r];
            out[ob + ((size_t)o << 14) + (h << 7) + w0 + nl] = softplus_fast(v);
        }
    }
}

extern "C" void kernel_launch(void* const* d_in, const int* in_sizes, int n_in,
                              void* d_out, int out_size, void* d_ws, size_t ws_size,
                              hipStream_t stream)
{
    const float* x   = (const float*)d_in[0];
    const float* wr  = (const float*)d_in[1];
    const float* br  = (const float*)d_in[2];
    const float* gam = (const float*)d_in[3];
    const float* bet = (const float*)d_in[4];
    const float* wsp = (const float*)d_in[5];
    const float* bsp = (const float*)d_in[6];
    const float* w2  = (const float*)d_in[7];
    const float* b2  = (const float*)d_in[8];
    float* out = (float*)d_out;

    // ws: zb bf16[NPIX*64] | wtr[4608*8] | wtr1[512*8] | wtr2[128*8] | stats f32[128] | zeros f32[128]
    unsigned short* zb   = (unsigned short*)d_ws;
    unsigned short* wtr  = zb + (size_t)NPIX * C_;
    unsigned short* wtr1 = wtr + 4608 * 8;
    unsigned short* wtr2 = wtr1 + 512 * 8;
    float* stats = (float*)(wtr2 + 128 * 8);

    // rb: bf16 pixel-major r in d_out scratch; fully consumed before k4.
    unsigned short* rb = (unsigned short*)d_out;

    k0_wtr<<<18, 256, 0, stream>>>(w2, wr, wsp, wtr, wtr1, wtr2, stats);
    k1_mfma<<<NPIX / 256, 256, 0, stream>>>(x, wtr1, br, rb, stats);
    k3_involution<<<NPIX / 256, 256, 0, stream>>>(x, rb, stats, gam, bet, wtr2, bsp, zb);
    k4_mfma<<<NPIX / 256, 256, 0, stream>>>(zb, wtr, b2, out);
}